// Round 6
// baseline (749.966 us; speedup 1.0000x reference)
//
#include <hip/hip_runtime.h>
#include <hip/hip_bf16.h>

// Problem constants (B=4, C=64, N=8192, K=16, D=64)
#define NPTS 8192
#define NQ   32768      // B*N
#define KNN  16

// ws layout (bytes)
#define OFF_XT   0                      // B*N*C f32 = 8 MB  (x transposed to (B,N,C))
#define OFF_FBIG (8*1024*1024)          // 17*64*64 f32 = 278528 B (F with appended -sum(F))
#define OFF_SUMS (OFF_FBIG + 278528)    // 128 f32 (sum, sumsq per channel)
#define OFF_IDX  (OFF_SUMS + 512)       // B*N*16 int32 = 2 MB
#define OFF_PRE  (OFF_IDX + 2*1024*1024)// B*N*64 f32 = 8 MB (pre-BN output, (B*N, D))

// Reference fp32 key — numpy execution model (round 6):
//   sq[m]   = (x*x + y*y) + z*z                  -- np.sum(pos*pos): products
//                                                   materialized, then strided
//                                                   adds -> NON-fused
//   inner   = fma(z,z', fma(y,y', rnd(x*x')))     -- np.einsum AVX2 axpy loop:
//                                                   out[m] += s*op[m] via
//                                                   npyv_muladd, c ascending
//   negd    = ((2*inner) - sq_n) - sq_m           -- elementwise, left-to-right
// Evidence: fully-fused key (R3/4) absmax 1.283; fully-non-fused (R5) 1.367;
// exact ranking (R1) 1.766 -> ref mixes FMA inner with non-fused sq.
__device__ __forceinline__ float sq3(float x, float y, float z) {
    #pragma clang fp contract(off)
    float xx = x * x;
    float yy = y * y;
    float zz = z * z;
    return (xx + yy) + zz;
}
__device__ __forceinline__ float negd_key(float qx, float qy, float qz, float sqn,
                                          float mx, float my, float mz) {
    #pragma clang fp contract(off)
    float p0 = qx * mx;                       // c=0: fma(x,x',0) == rnd(x*x')
    float inn = __builtin_fmaf(qz, mz, __builtin_fmaf(qy, my, p0));
    float sqm = sq3(mx, my, mz);
    float t = 2.0f * inn;                     // exact (scale by 2)
    float u = t - sqn;
    return u - sqm;
}

// ---------------- K0a: transpose x (B,C,N) -> xT (B,N,C) ----------------
__global__ __launch_bounds__(256) void k_prep_x(const float* __restrict__ x,
                                                float* __restrict__ xT) {
    __shared__ float tile[64][65];
    int lane = threadIdx.x & 63, wid = threadIdx.x >> 6;
    int b = blockIdx.x >> 7, nt = blockIdx.x & 127;
    int n0 = nt * 64;
    for (int rr = 0; rr < 16; ++rr) {
        int c = wid * 16 + rr;
        tile[c][lane] = x[((size_t)b * 64 + c) * NPTS + n0 + lane];
    }
    __syncthreads();
    for (int rr = 0; rr < 16; ++rr) {
        int r = wid * 16 + rr;
        xT[((size_t)(b * NPTS + n0 + r)) * 64 + lane] = tile[lane][r];
    }
}

// ---------------- K0b: Fbig[j]=F[j] (j<16), Fbig[16]=-sum_k F[k]; zero sums ----
__global__ __launch_bounds__(256) void k_prep_f(const float* __restrict__ F,
                                                float* __restrict__ Fb,
                                                float* __restrict__ sums) {
    int j = blockIdx.x;
    if (j < 16) {
        for (int e = threadIdx.x; e < 4096; e += 256)
            Fb[j * 4096 + e] = F[j * 4096 + e];
    } else if (j == 16) {
        for (int e = threadIdx.x; e < 4096; e += 256) {
            float s = 0.f;
            for (int k = 0; k < 16; ++k) s += F[k * 4096 + e];
            Fb[16 * 4096 + e] = -s;
        }
    } else {
        if (threadIdx.x < 128) sums[threadIdx.x] = 0.f;
    }
}

// ---------------- K1: kNN by reference fp32 key (wave/query) -----------------
// Rank by negd (descending), ties -> lower index (stable, lax.top_k/argsort).
// Pass1: per-lane MAX of negd -> tau = 16th largest of the 64 lane maxima.
// tau <= true 16th-best key, so {negd >= tau} is a superset of the true top-16.
// Pass2 collects that set, then full rerank among survivors.
__global__ __launch_bounds__(256) void k_knn(const float* __restrict__ pos,
                                             int* __restrict__ idxo) {
    __shared__ int   cnt[4];
    __shared__ int   sidx[4][128];
    __shared__ float skey[4][128];
    __shared__ int   outI[4][16];
    int lane = threadIdx.x & 63, wid = threadIdx.x >> 6;
    int q = blockIdx.x * 4 + wid;
    int b = q >> 13, n = q & (NPTS - 1);
    const float* pb = pos + (size_t)b * 3 * NPTS;
    float qx = pb[n], qy = pb[NPTS + n], qz = pb[2 * NPTS + n];
    float sqn = sq3(qx, qy, qz);
    if (lane == 0) cnt[wid] = 0;
    if (lane < 16) outI[wid][lane] = n;   // fallback: self (always in-range)

    // pass 1: per-lane maximum of negd
    float lanemax = -3.4e38f;
    #pragma unroll 4
    for (int t = 0; t < 128; ++t) {
        int m = t * 64 + lane;
        float k = negd_key(qx, qy, qz, sqn, pb[m], pb[NPTS + m], pb[2 * NPTS + m]);
        lanemax = fmaxf(lanemax, k);
    }

    // tau = 16th largest of the 64 lane maxima (butterfly-max, pop 16x).
    // Ties pop multiple lanes at once -> tau only shrinks -> still a superset.
    float val = lanemax, tau = 0.f;
    for (int r = 0; r < 16; ++r) {
        float mm = val;
        mm = fmaxf(mm, __shfl_xor(mm, 1, 64));
        mm = fmaxf(mm, __shfl_xor(mm, 2, 64));
        mm = fmaxf(mm, __shfl_xor(mm, 4, 64));
        mm = fmaxf(mm, __shfl_xor(mm, 8, 64));
        mm = fmaxf(mm, __shfl_xor(mm, 16, 64));
        mm = fmaxf(mm, __shfl_xor(mm, 32, 64));
        tau = mm;
        if (val == mm) val = -3.4e38f;
    }

    // pass 2: collect survivors (expected ~20-40)
    #pragma unroll 4
    for (int t = 0; t < 128; ++t) {
        int m = t * 64 + lane;
        float k = negd_key(qx, qy, qz, sqn, pb[m], pb[NPTS + m], pb[2 * NPTS + m]);
        if (k >= tau) {
            int slot = atomicAdd(&cnt[wid], 1);
            if (slot < 128) { sidx[wid][slot] = m; skey[wid][slot] = k; }
        }
    }
    __syncthreads();

    int S = cnt[wid]; if (S > 128) S = 128;
    // full ranking of survivors; write top-16 (staged in LDS)
    for (int p = lane; p < S; p += 64) {
        int m = sidx[wid][p];
        float km = skey[wid][p];
        int rank = 0;
        for (int j = 0; j < S; ++j) {
            float kj = skey[wid][j];
            int ij = sidx[wid][j];
            if (kj > km || (kj == km && ij < m)) rank++;
        }
        if (rank < KNN) outI[wid][rank] = m;
    }
    __syncthreads();
    if (lane < 16) idxo[(size_t)q * KNN + lane] = outI[wid][lane];
}

// ---------------- K2: gather + filter contraction (wave per query) ------------
// outp[q][d] = sum_{j=0..16} sum_c xT[nbr_j][c] * Fbig[j][c][d],
// with nbr_16 = self and Fbig[16] = -sum_k F[k].
__global__ __launch_bounds__(256) void k_conv(const float* __restrict__ xT,
                                              const float* __restrict__ Fb,
                                              const int* __restrict__ idx,
                                              float* __restrict__ outp) {
    int lane = threadIdx.x & 63, wid = threadIdx.x >> 6;
    int q = blockIdx.x * 4 + wid;
    int b = q >> 13, n = q & (NPTS - 1);
    const float* xTb = xT + (size_t)b * NPTS * 64;
    const int* iq = idx + (size_t)q * KNN;
    float vself = xTb[(size_t)n * 64 + lane];
    float acc = 0.f;
    #pragma unroll 1
    for (int j = 0; j < 17; ++j) {
        // mask keeps any (theoretically impossible) bad index in-range:
        // converts a would-be fault into a measurable numeric error.
        int nbr = (j < 16) ? (iq[j] & (NPTS - 1)) : n;
        float v = (j < 16) ? xTb[(size_t)nbr * 64 + lane] : vself;
        const float* Fp = Fb + j * 4096 + lane;
        #pragma unroll
        for (int c = 0; c < 64; ++c) {
            float vc = __shfl(v, c, 64);
            acc = fmaf(vc, Fp[c * 64], acc);
        }
    }
    outp[(size_t)q * 64 + lane] = acc;
}

// ---------------- K3: per-channel sum / sumsq ----------------
__global__ __launch_bounds__(256) void k_stats(const float* __restrict__ outp,
                                               float* __restrict__ sums) {
    __shared__ float ls[4][64], lss[4][64];
    int lane = threadIdx.x & 63, wid = threadIdx.x >> 6;
    int gw = blockIdx.x * 4 + wid;         // 1024 waves, 32 rows each
    float s = 0.f, ss = 0.f;
    for (int r = gw * 32; r < gw * 32 + 32; ++r) {
        float v = outp[(size_t)r * 64 + lane];
        s += v; ss = fmaf(v, v, ss);
    }
    ls[wid][lane] = s; lss[wid][lane] = ss;
    __syncthreads();
    if (wid == 0) {
        float a = 0.f, b2 = 0.f;
        for (int w = 0; w < 4; ++w) { a += ls[w][lane]; b2 += lss[w][lane]; }
        atomicAdd(&sums[lane], a);
        atomicAdd(&sums[64 + lane], b2);
    }
}

// ---------------- K4: BN + transpose (B,N,D) -> (B,D,N) ----------------
__global__ __launch_bounds__(256) void k_bn(const float* __restrict__ outp,
                                            const float* __restrict__ sums,
                                            const float* __restrict__ gamma,
                                            const float* __restrict__ beta,
                                            float* __restrict__ out) {
    __shared__ float tile[64][65];
    __shared__ float sa[64], sb[64];
    int lane = threadIdx.x & 63, wid = threadIdx.x >> 6;
    int b = blockIdx.x >> 7, nt = blockIdx.x & 127;
    int n0 = nt * 64;
    if (threadIdx.x < 64) {
        const float inv = 1.f / 32768.f;
        float mean = sums[threadIdx.x] * inv;
        float var = sums[64 + threadIdx.x] * inv - mean * mean;
        float rs = rsqrtf(var + 1e-5f);
        float a = rs * gamma[threadIdx.x];
        sa[threadIdx.x] = a;
        sb[threadIdx.x] = beta[threadIdx.x] - mean * a;
    }
    for (int rr = 0; rr < 16; ++rr) {
        int r = wid * 16 + rr;
        tile[r][lane] = outp[((size_t)(b * NPTS + n0 + r)) * 64 + lane];
    }
    __syncthreads();
    for (int rr = 0; rr < 16; ++rr) {
        int dr = wid * 16 + rr;
        out[((size_t)b * 64 + dr) * NPTS + n0 + lane] =
            fmaf(tile[lane][dr], sa[dr], sb[dr]);
    }
}

extern "C" void kernel_launch(void* const* d_in, const int* in_sizes, int n_in,
                              void* d_out, int out_size, void* d_ws, size_t ws_size,
                              hipStream_t stream) {
    (void)in_sizes; (void)n_in; (void)out_size; (void)ws_size;
    const float* x     = (const float*)d_in[0];  // (4,64,8192)
    const float* pos   = (const float*)d_in[1];  // (4,3,8192)
    const float* F     = (const float*)d_in[2];  // (16,64,64)
    const float* gamma = (const float*)d_in[3];  // (64,)
    const float* beta  = (const float*)d_in[4];  // (64,)
    float* out = (float*)d_out;                  // (4,64,8192)

    char* ws = (char*)d_ws;
    float* xT   = (float*)(ws + OFF_XT);
    float* Fb   = (float*)(ws + OFF_FBIG);
    float* sums = (float*)(ws + OFF_SUMS);
    int*   idx  = (int*)(ws + OFF_IDX);
    float* pre  = (float*)(ws + OFF_PRE);

    k_prep_x<<<512, 256, 0, stream>>>(x, xT);
    k_prep_f<<<18, 256, 0, stream>>>(F, Fb, sums);
    k_knn<<<8192, 256, 0, stream>>>(pos, idx);
    k_conv<<<8192, 256, 0, stream>>>(xT, Fb, idx, pre);
    k_stats<<<256, 256, 0, stream>>>(pre, sums);
    k_bn<<<512, 256, 0, stream>>>(pre, sums, gamma, beta, out);
}

// Round 7
// 408.327 us; speedup vs baseline: 1.8367x; 1.8367x over previous
//
#include <hip/hip_runtime.h>
#include <hip/hip_bf16.h>

// Problem constants (B=4, C=64, N=8192, K=16, D=64)
#define NPTS 8192
#define NQ   32768      // B*N
#define KNN  16

// ws layout (bytes)
#define OFF_XT   0                      // B*N*C f32 = 8 MB  (x transposed to (B,N,C))
#define OFF_FBIG (8*1024*1024)          // 17*64*64 f32 = 278528 B (F with appended -sum(F))
#define OFF_SUMS (OFF_FBIG + 278528)    // 128 f32 (sum, sumsq per channel)
#define OFF_IDX  (OFF_SUMS + 512)       // B*N*16 int32 = 2 MB
#define OFF_PRE  (OFF_IDX + 2*1024*1024)// B*N*64 f32 = 8 MB (pre-BN output, (B*N, D))
// sq array (B*N f32 = 128 KB) ALIASES the start of PRE: k_prep_sq writes it,
// k_knn consumes it, then k_conv overwrites PRE — stream-ordered, safe.
#define OFF_SQ   OFF_PRE

// Reference fp32 key — numpy execution model (verified R6, absmax 0.0156):
//   sq[m]   = (x*x + y*y) + z*z                  -- non-fused (np.sum(pos*pos))
//   inner   = fma(z,z', fma(y,y', rnd(x*x')))    -- einsum AVX2 axpy FMA chain
//   negd    = ((2*inner) - sq_n) - sq_m          -- elementwise, left-to-right
__device__ __forceinline__ float sq3(float x, float y, float z) {
    #pragma clang fp contract(off)
    float xx = x * x;
    float yy = y * y;
    float zz = z * z;
    return (xx + yy) + zz;
}
__device__ __forceinline__ float negd2(float qx, float qy, float qz, float sqn,
                                       float mx, float my, float mz, float sqm) {
    #pragma clang fp contract(off)
    float p0 = qx * mx;
    float inn = __builtin_fmaf(qz, mz, __builtin_fmaf(qy, my, p0));
    float t = 2.0f * inn;
    float u = t - sqn;
    return u - sqm;
}

// ---------------- K0a: transpose x (B,C,N) -> xT (B,N,C) ----------------
__global__ __launch_bounds__(256) void k_prep_x(const float* __restrict__ x,
                                                float* __restrict__ xT) {
    __shared__ float tile[64][65];
    int lane = threadIdx.x & 63, wid = threadIdx.x >> 6;
    int b = blockIdx.x >> 7, nt = blockIdx.x & 127;
    int n0 = nt * 64;
    for (int rr = 0; rr < 16; ++rr) {
        int c = wid * 16 + rr;
        tile[c][lane] = x[((size_t)b * 64 + c) * NPTS + n0 + lane];
    }
    __syncthreads();
    for (int rr = 0; rr < 16; ++rr) {
        int r = wid * 16 + rr;
        xT[((size_t)(b * NPTS + n0 + r)) * 64 + lane] = tile[lane][r];
    }
}

// ---------------- K0b: Fbig[j]=F[j] (j<16), Fbig[16]=-sum_k F[k]; zero sums ----
__global__ __launch_bounds__(256) void k_prep_f(const float* __restrict__ F,
                                                float* __restrict__ Fb,
                                                float* __restrict__ sums) {
    int j = blockIdx.x;
    if (j < 16) {
        for (int e = threadIdx.x; e < 4096; e += 256)
            Fb[j * 4096 + e] = F[j * 4096 + e];
    } else if (j == 16) {
        for (int e = threadIdx.x; e < 4096; e += 256) {
            float s = 0.f;
            for (int k = 0; k < 16; ++k) s += F[k * 4096 + e];
            Fb[16 * 4096 + e] = -s;
        }
    } else {
        if (threadIdx.x < 128) sums[threadIdx.x] = 0.f;
    }
}

// ---------------- K0c: per-point sq (exact reference rounding) ----------------
__global__ __launch_bounds__(256) void k_prep_sq(const float* __restrict__ pos,
                                                 float* __restrict__ sqa) {
    int g = blockIdx.x * 256 + threadIdx.x;   // 0..NQ-1
    int b = g >> 13, n = g & (NPTS - 1);
    const float* pb = pos + (size_t)b * 3 * NPTS;
    sqa[g] = sq3(pb[n], pb[NPTS + n], pb[2 * NPTS + n]);
}

// ---------------- K1: kNN by reference fp32 key (wave/query) -----------------
// float4 candidate loads (4 cand/lane/iter) + precomputed sq.
__global__ __launch_bounds__(256) void k_knn(const float* __restrict__ pos,
                                             const float* __restrict__ sqa,
                                             int* __restrict__ idxo) {
    __shared__ int   cnt[4];
    __shared__ int   sidx[4][128];
    __shared__ float skey[4][128];
    __shared__ int   outI[4][16];
    int lane = threadIdx.x & 63, wid = threadIdx.x >> 6;
    int q = blockIdx.x * 4 + wid;
    int b = q >> 13, n = q & (NPTS - 1);
    const float* px = pos + (size_t)b * 3 * NPTS;
    const float* py = px + NPTS;
    const float* pz = py + NPTS;
    const float* sb = sqa + (size_t)b * NPTS;
    float qx = px[n], qy = py[n], qz = pz[n];
    float sqn = sb[n];
    if (lane == 0) cnt[wid] = 0;
    if (lane < 16) outI[wid][lane] = n;   // fallback: self (always in-range)

    // pass 1: per-lane maximum of negd over 4 candidates per iteration
    float lanemax = -3.4e38f;
    for (int t = 0; t < 32; ++t) {
        int m = t * 256 + lane * 4;
        float4 X = *(const float4*)(px + m);
        float4 Y = *(const float4*)(py + m);
        float4 Z = *(const float4*)(pz + m);
        float4 S = *(const float4*)(sb + m);
        lanemax = fmaxf(lanemax, negd2(qx,qy,qz,sqn, X.x,Y.x,Z.x, S.x));
        lanemax = fmaxf(lanemax, negd2(qx,qy,qz,sqn, X.y,Y.y,Z.y, S.y));
        lanemax = fmaxf(lanemax, negd2(qx,qy,qz,sqn, X.z,Y.z,Z.z, S.z));
        lanemax = fmaxf(lanemax, negd2(qx,qy,qz,sqn, X.w,Y.w,Z.w, S.w));
    }

    // tau = 16th largest of the 64 lane maxima (butterfly-max, pop 16x).
    float val = lanemax, tau = 0.f;
    for (int r = 0; r < 16; ++r) {
        float mm = val;
        mm = fmaxf(mm, __shfl_xor(mm, 1, 64));
        mm = fmaxf(mm, __shfl_xor(mm, 2, 64));
        mm = fmaxf(mm, __shfl_xor(mm, 4, 64));
        mm = fmaxf(mm, __shfl_xor(mm, 8, 64));
        mm = fmaxf(mm, __shfl_xor(mm, 16, 64));
        mm = fmaxf(mm, __shfl_xor(mm, 32, 64));
        tau = mm;
        if (val == mm) val = -3.4e38f;
    }

    // pass 2: collect survivors (expected ~20-40)
    for (int t = 0; t < 32; ++t) {
        int m = t * 256 + lane * 4;
        float4 X = *(const float4*)(px + m);
        float4 Y = *(const float4*)(py + m);
        float4 Z = *(const float4*)(pz + m);
        float4 S = *(const float4*)(sb + m);
        float k0 = negd2(qx,qy,qz,sqn, X.x,Y.x,Z.x, S.x);
        float k1 = negd2(qx,qy,qz,sqn, X.y,Y.y,Z.y, S.y);
        float k2 = negd2(qx,qy,qz,sqn, X.z,Y.z,Z.z, S.z);
        float k3 = negd2(qx,qy,qz,sqn, X.w,Y.w,Z.w, S.w);
        if (k0 >= tau) { int s = atomicAdd(&cnt[wid],1); if (s<128){sidx[wid][s]=m;   skey[wid][s]=k0;} }
        if (k1 >= tau) { int s = atomicAdd(&cnt[wid],1); if (s<128){sidx[wid][s]=m+1; skey[wid][s]=k1;} }
        if (k2 >= tau) { int s = atomicAdd(&cnt[wid],1); if (s<128){sidx[wid][s]=m+2; skey[wid][s]=k2;} }
        if (k3 >= tau) { int s = atomicAdd(&cnt[wid],1); if (s<128){sidx[wid][s]=m+3; skey[wid][s]=k3;} }
    }
    __syncthreads();

    int S = cnt[wid]; if (S > 128) S = 128;
    // full ranking of survivors; write top-16 (staged in LDS)
    for (int p = lane; p < S; p += 64) {
        int m = sidx[wid][p];
        float km = skey[wid][p];
        int rank = 0;
        for (int j = 0; j < S; ++j) {
            float kj = skey[wid][j];
            int ij = sidx[wid][j];
            if (kj > km || (kj == km && ij < m)) rank++;
        }
        if (rank < KNN) outI[wid][rank] = m;
    }
    __syncthreads();
    if (lane < 16) idxo[(size_t)q * KNN + lane] = outI[wid][lane];
}

// ---------------- K2: gather + filter contraction as LDS-tiled GEMM ----------
// outp[q][d] = sum_{j=0..16} sum_c xT[nbr_j(q)][c] * Fbig[j][c][d]
// Tile: 64 queries x 64 d per block; K-loop over j (17) x c (64).
// At[c][q] (pad 68) = gathered edge rows transposed; Bt[c][d] = F[j].
// Per-thread 4x4 micro-tile => 16 FMA per 2 ds_read_b128.
// Accumulation order (j outer, c ascending) identical to R6 => bit-stable.
#define CPAD 68
__global__ __launch_bounds__(256) void k_conv(const float* __restrict__ xT,
                                              const float* __restrict__ Fb,
                                              const int* __restrict__ idx,
                                              float* __restrict__ outp) {
    __shared__ float At[64][CPAD];
    __shared__ float Bt[64 * 64];
    int t = threadIdx.x;
    int q0 = blockIdx.x * 64;                 // tile base (same batch: 8192%64==0)
    int bbase = q0 & ~(NPTS - 1);             // batch row offset in xT
    int qi0 = (t >> 4) * 4;                   // query sub-block 0..60
    int dj0 = (t & 15) * 4;                   // d sub-block 0..60
    int r = t & 63;                           // gather row
    int s = t >> 6;                           // 16-float segment

    float acc[4][4];
    #pragma unroll
    for (int a = 0; a < 4; ++a)
        #pragma unroll
        for (int bb = 0; bb < 4; ++bb) acc[a][bb] = 0.f;

    for (int j = 0; j < 17; ++j) {
        // ---- stage A: gather 64 neighbor rows, store transposed ----
        {
            int qg = q0 + r;
            int nbr = (j < 16) ? (idx[(size_t)qg * KNN + j] & (NPTS - 1))
                               : (qg & (NPTS - 1));
            const float* src = xT + ((size_t)(bbase + nbr) * 64 + s * 16);
            float4 v0 = *(const float4*)(src);
            float4 v1 = *(const float4*)(src + 4);
            float4 v2 = *(const float4*)(src + 8);
            float4 v3 = *(const float4*)(src + 12);
            int c0 = s * 16;
            At[c0+ 0][r] = v0.x; At[c0+ 1][r] = v0.y; At[c0+ 2][r] = v0.z; At[c0+ 3][r] = v0.w;
            At[c0+ 4][r] = v1.x; At[c0+ 5][r] = v1.y; At[c0+ 6][r] = v1.z; At[c0+ 7][r] = v1.w;
            At[c0+ 8][r] = v2.x; At[c0+ 9][r] = v2.y; At[c0+10][r] = v2.z; At[c0+11][r] = v2.w;
            At[c0+12][r] = v3.x; At[c0+13][r] = v3.y; At[c0+14][r] = v3.z; At[c0+15][r] = v3.w;
        }
        // ---- stage B: copy F[j] (4096 floats) ----
        {
            const float* fj = Fb + j * 4096;
            #pragma unroll
            for (int u = 0; u < 4; ++u) {
                int e = u * 1024 + t * 4;
                *(float4*)&Bt[e] = *(const float4*)(fj + e);
            }
        }
        __syncthreads();
        // ---- compute: 64 k-steps ----
        #pragma unroll 8
        for (int k = 0; k < 64; ++k) {
            float4 av = *(const float4*)&At[k][qi0];
            float4 bv = *(const float4*)&Bt[k * 64 + dj0];
            acc[0][0] = fmaf(av.x, bv.x, acc[0][0]);
            acc[0][1] = fmaf(av.x, bv.y, acc[0][1]);
            acc[0][2] = fmaf(av.x, bv.z, acc[0][2]);
            acc[0][3] = fmaf(av.x, bv.w, acc[0][3]);
            acc[1][0] = fmaf(av.y, bv.x, acc[1][0]);
            acc[1][1] = fmaf(av.y, bv.y, acc[1][1]);
            acc[1][2] = fmaf(av.y, bv.z, acc[1][2]);
            acc[1][3] = fmaf(av.y, bv.w, acc[1][3]);
            acc[2][0] = fmaf(av.z, bv.x, acc[2][0]);
            acc[2][1] = fmaf(av.z, bv.y, acc[2][1]);
            acc[2][2] = fmaf(av.z, bv.z, acc[2][2]);
            acc[2][3] = fmaf(av.z, bv.w, acc[2][3]);
            acc[3][0] = fmaf(av.w, bv.x, acc[3][0]);
            acc[3][1] = fmaf(av.w, bv.y, acc[3][1]);
            acc[3][2] = fmaf(av.w, bv.z, acc[3][2]);
            acc[3][3] = fmaf(av.w, bv.w, acc[3][3]);
        }
        __syncthreads();
    }
    // ---- epilogue ----
    #pragma unroll
    for (int qi = 0; qi < 4; ++qi) {
        float4 o = make_float4(acc[qi][0], acc[qi][1], acc[qi][2], acc[qi][3]);
        *(float4*)(outp + (size_t)(q0 + qi0 + qi) * 64 + dj0) = o;
    }
}

// ---------------- K3: per-channel sum / sumsq ----------------
__global__ __launch_bounds__(256) void k_stats(const float* __restrict__ outp,
                                               float* __restrict__ sums) {
    __shared__ float ls[4][64], lss[4][64];
    int lane = threadIdx.x & 63, wid = threadIdx.x >> 6;
    int gw = blockIdx.x * 4 + wid;         // 1024 waves, 32 rows each
    float s = 0.f, ss = 0.f;
    for (int r = gw * 32; r < gw * 32 + 32; ++r) {
        float v = outp[(size_t)r * 64 + lane];
        s += v; ss = fmaf(v, v, ss);
    }
    ls[wid][lane] = s; lss[wid][lane] = ss;
    __syncthreads();
    if (wid == 0) {
        float a = 0.f, b2 = 0.f;
        for (int w = 0; w < 4; ++w) { a += ls[w][lane]; b2 += lss[w][lane]; }
        atomicAdd(&sums[lane], a);
        atomicAdd(&sums[64 + lane], b2);
    }
}

// ---------------- K4: BN + transpose (B,N,D) -> (B,D,N) ----------------
__global__ __launch_bounds__(256) void k_bn(const float* __restrict__ outp,
                                            const float* __restrict__ sums,
                                            const float* __restrict__ gamma,
                                            const float* __restrict__ beta,
                                            float* __restrict__ out) {
    __shared__ float tile[64][65];
    __shared__ float sa[64], sb[64];
    int lane = threadIdx.x & 63, wid = threadIdx.x >> 6;
    int b = blockIdx.x >> 7, nt = blockIdx.x & 127;
    int n0 = nt * 64;
    if (threadIdx.x < 64) {
        const float inv = 1.f / 32768.f;
        float mean = sums[threadIdx.x] * inv;
        float var = sums[64 + threadIdx.x] * inv - mean * mean;
        float rs = rsqrtf(var + 1e-5f);
        float a = rs * gamma[threadIdx.x];
        sa[threadIdx.x] = a;
        sb[threadIdx.x] = beta[threadIdx.x] - mean * a;
    }
    for (int rr = 0; rr < 16; ++rr) {
        int r = wid * 16 + rr;
        tile[r][lane] = outp[((size_t)(b * NPTS + n0 + r)) * 64 + lane];
    }
    __syncthreads();
    for (int rr = 0; rr < 16; ++rr) {
        int dr = wid * 16 + rr;
        out[((size_t)b * 64 + dr) * NPTS + n0 + lane] =
            fmaf(tile[lane][dr], sa[dr], sb[dr]);
    }
}

extern "C" void kernel_launch(void* const* d_in, const int* in_sizes, int n_in,
                              void* d_out, int out_size, void* d_ws, size_t ws_size,
                              hipStream_t stream) {
    (void)in_sizes; (void)n_in; (void)out_size; (void)ws_size;
    const float* x     = (const float*)d_in[0];  // (4,64,8192)
    const float* pos   = (const float*)d_in[1];  // (4,3,8192)
    const float* F     = (const float*)d_in[2];  // (16,64,64)
    const float* gamma = (const float*)d_in[3];  // (64,)
    const float* beta  = (const float*)d_in[4];  // (64,)
    float* out = (float*)d_out;                  // (4,64,8192)

    char* ws = (char*)d_ws;
    float* xT   = (float*)(ws + OFF_XT);
    float* Fb   = (float*)(ws + OFF_FBIG);
    float* sums = (float*)(ws + OFF_SUMS);
    int*   idx  = (int*)(ws + OFF_IDX);
    float* pre  = (float*)(ws + OFF_PRE);
    float* sqa  = (float*)(ws + OFF_SQ);   // aliases pre; consumed before conv

    k_prep_x<<<512, 256, 0, stream>>>(x, xT);
    k_prep_f<<<18, 256, 0, stream>>>(F, Fb, sums);
    k_prep_sq<<<128, 256, 0, stream>>>(pos, sqa);
    k_knn<<<8192, 256, 0, stream>>>(pos, sqa, idx);
    k_conv<<<512, 256, 0, stream>>>(xT, Fb, idx, pre);
    k_stats<<<256, 256, 0, stream>>>(pre, sums);
    k_bn<<<512, 256, 0, stream>>>(pre, sums, gamma, beta, out);
}

// Round 8
// 312.592 us; speedup vs baseline: 2.3992x; 1.3063x over previous
//
#include <hip/hip_runtime.h>
#include <hip/hip_bf16.h>

// Problem constants (B=4, C=64, N=8192, K=16, D=64)
#define NPTS 8192
#define NQ   32768      // B*N
#define KNN  16

// ws layout (bytes)
#define OFF_XT   0                      // B*N*C f32 = 8 MB  (x transposed to (B,N,C))
#define OFF_FBIG (8*1024*1024)          // 17*64*64 f32 = 278528 B (F with appended -sum(F))
#define OFF_SUMS (OFF_FBIG + 278528)    // 128 f32 (sum, sumsq per channel)
#define OFF_IDX  (OFF_SUMS + 512)       // B*N*16 int32 = 2 MB
#define OFF_PRE  (OFF_IDX + 2*1024*1024)// B*N*64 f32 = 8 MB (pre-BN output, (B*N, D))
// sq array (B*N f32 = 128 KB) ALIASES the start of PRE: k_prep_sq writes it,
// k_knn consumes it, then k_conv overwrites PRE — stream-ordered, safe.
#define OFF_SQ   OFF_PRE

// Reference fp32 key — numpy execution model (verified R6, absmax 0.0156):
//   sq[m]   = (x*x + y*y) + z*z                  -- non-fused (np.sum(pos*pos))
//   inner   = fma(z,z', fma(y,y', rnd(x*x')))    -- einsum AVX2 axpy FMA chain
//   negd    = ((2*inner) - sq_n) - sq_m          -- elementwise, left-to-right
__device__ __forceinline__ float sq3(float x, float y, float z) {
    #pragma clang fp contract(off)
    float xx = x * x;
    float yy = y * y;
    float zz = z * z;
    return (xx + yy) + zz;
}
__device__ __forceinline__ float negd2(float qx, float qy, float qz, float sqn,
                                       float mx, float my, float mz, float sqm) {
    #pragma clang fp contract(off)
    float p0 = qx * mx;
    float inn = __builtin_fmaf(qz, mz, __builtin_fmaf(qy, my, p0));
    float t = 2.0f * inn;
    float u = t - sqn;
    return u - sqm;
}

// ---------------- K0a: transpose x (B,C,N) -> xT (B,N,C) ----------------
__global__ __launch_bounds__(256) void k_prep_x(const float* __restrict__ x,
                                                float* __restrict__ xT) {
    __shared__ float tile[64][65];
    int lane = threadIdx.x & 63, wid = threadIdx.x >> 6;
    int b = blockIdx.x >> 7, nt = blockIdx.x & 127;
    int n0 = nt * 64;
    for (int rr = 0; rr < 16; ++rr) {
        int c = wid * 16 + rr;
        tile[c][lane] = x[((size_t)b * 64 + c) * NPTS + n0 + lane];
    }
    __syncthreads();
    for (int rr = 0; rr < 16; ++rr) {
        int r = wid * 16 + rr;
        xT[((size_t)(b * NPTS + n0 + r)) * 64 + lane] = tile[lane][r];
    }
}

// ---------------- K0b: Fbig[j]=F[j] (j<16), Fbig[16]=-sum_k F[k]; zero sums ----
__global__ __launch_bounds__(256) void k_prep_f(const float* __restrict__ F,
                                                float* __restrict__ Fb,
                                                float* __restrict__ sums) {
    int j = blockIdx.x;
    if (j < 16) {
        for (int e = threadIdx.x; e < 4096; e += 256)
            Fb[j * 4096 + e] = F[j * 4096 + e];
    } else if (j == 16) {
        for (int e = threadIdx.x; e < 4096; e += 256) {
            float s = 0.f;
            for (int k = 0; k < 16; ++k) s += F[k * 4096 + e];
            Fb[16 * 4096 + e] = -s;
        }
    } else {
        if (threadIdx.x < 128) sums[threadIdx.x] = 0.f;
    }
}

// ---------------- K0c: per-point sq (exact reference rounding) ----------------
__global__ __launch_bounds__(256) void k_prep_sq(const float* __restrict__ pos,
                                                 float* __restrict__ sqa) {
    int g = blockIdx.x * 256 + threadIdx.x;   // 0..NQ-1
    int b = g >> 13, n = g & (NPTS - 1);
    const float* pb = pos + (size_t)b * 3 * NPTS;
    sqa[g] = sq3(pb[n], pb[NPTS + n], pb[2 * NPTS + n]);
}

// ---------------- K1: kNN, 8 queries per wave (cache-traffic / 8) ------------
// Each wave serves 8 consecutive queries; one float4 candidate load feeds
// 8 key evals. Per-query: tau = 16th-largest of 64 lane-maxima (superset
// bound), collect survivors >= tau into wave-private LDS lists, exact rerank.
__global__ __launch_bounds__(256) void k_knn(const float* __restrict__ pos,
                                             const float* __restrict__ sqa,
                                             int* __restrict__ idxo) {
    __shared__ int   cnt[32];
    __shared__ int   sidx[32][128];
    __shared__ float skey[32][128];
    __shared__ int   outI[32][16];
    int t = threadIdx.x, lane = t & 63, wid = t >> 6;
    int qblk = blockIdx.x * 32;               // 32 queries per block, same batch
    int b = qblk >> 13;
    const float* px = pos + (size_t)b * 3 * NPTS;
    const float* py = px + NPTS;
    const float* pz = py + NPTS;
    const float* sb = sqa + (size_t)b * NPTS;
    int n0 = (qblk & (NPTS - 1)) + wid * 8;   // this wave's first query

    float qxs[8], qys[8], qzs[8], sqs[8];
    #pragma unroll
    for (int i = 0; i < 8; ++i) {
        qxs[i] = px[n0 + i]; qys[i] = py[n0 + i];
        qzs[i] = pz[n0 + i]; sqs[i] = sb[n0 + i];
    }
    if (lane < 8) cnt[wid * 8 + lane] = 0;    // wave-private: no block sync
    if (lane < 16) {
        #pragma unroll
        for (int i = 0; i < 8; ++i) outI[wid * 8 + i][lane] = n0 + i;  // fallback
    }

    // pass 1: per-lane max of negd, per query
    float lm[8];
    #pragma unroll
    for (int i = 0; i < 8; ++i) lm[i] = -3.4e38f;
    for (int it = 0; it < 32; ++it) {
        int m = it * 256 + lane * 4;
        float4 X = *(const float4*)(px + m);
        float4 Y = *(const float4*)(py + m);
        float4 Z = *(const float4*)(pz + m);
        float4 S = *(const float4*)(sb + m);
        #pragma unroll
        for (int i = 0; i < 8; ++i) {
            float a0 = negd2(qxs[i],qys[i],qzs[i],sqs[i], X.x,Y.x,Z.x, S.x);
            float a1 = negd2(qxs[i],qys[i],qzs[i],sqs[i], X.y,Y.y,Z.y, S.y);
            float a2 = negd2(qxs[i],qys[i],qzs[i],sqs[i], X.z,Y.z,Z.z, S.z);
            float a3 = negd2(qxs[i],qys[i],qzs[i],sqs[i], X.w,Y.w,Z.w, S.w);
            lm[i] = fmaxf(lm[i], fmaxf(fmaxf(a0, a1), fmaxf(a2, a3)));
        }
    }

    // tau[i] = 16th largest of the 64 lane maxima (butterfly-max, pop 16x).
    // Ties pop multiple lanes at once -> tau only shrinks -> still a superset.
    float tau[8];
    #pragma unroll
    for (int i = 0; i < 8; ++i) {
        float val = lm[i], tv = 0.f;
        for (int r = 0; r < 16; ++r) {
            float mm = val;
            mm = fmaxf(mm, __shfl_xor(mm, 1, 64));
            mm = fmaxf(mm, __shfl_xor(mm, 2, 64));
            mm = fmaxf(mm, __shfl_xor(mm, 4, 64));
            mm = fmaxf(mm, __shfl_xor(mm, 8, 64));
            mm = fmaxf(mm, __shfl_xor(mm, 16, 64));
            mm = fmaxf(mm, __shfl_xor(mm, 32, 64));
            tv = mm;
            if (val == mm) val = -3.4e38f;
        }
        tau[i] = tv;
    }

    // pass 2: collect survivors per query (expected ~20-40 each)
    for (int it = 0; it < 32; ++it) {
        int m = it * 256 + lane * 4;
        float4 X = *(const float4*)(px + m);
        float4 Y = *(const float4*)(py + m);
        float4 Z = *(const float4*)(pz + m);
        float4 S = *(const float4*)(sb + m);
        #pragma unroll
        for (int i = 0; i < 8; ++i) {
            int lq = wid * 8 + i;
            float a0 = negd2(qxs[i],qys[i],qzs[i],sqs[i], X.x,Y.x,Z.x, S.x);
            float a1 = negd2(qxs[i],qys[i],qzs[i],sqs[i], X.y,Y.y,Z.y, S.y);
            float a2 = negd2(qxs[i],qys[i],qzs[i],sqs[i], X.z,Y.z,Z.z, S.z);
            float a3 = negd2(qxs[i],qys[i],qzs[i],sqs[i], X.w,Y.w,Z.w, S.w);
            if (a0 >= tau[i]) { int s_ = atomicAdd(&cnt[lq],1); if (s_<128){sidx[lq][s_]=m;   skey[lq][s_]=a0;} }
            if (a1 >= tau[i]) { int s_ = atomicAdd(&cnt[lq],1); if (s_<128){sidx[lq][s_]=m+1; skey[lq][s_]=a1;} }
            if (a2 >= tau[i]) { int s_ = atomicAdd(&cnt[lq],1); if (s_<128){sidx[lq][s_]=m+2; skey[lq][s_]=a2;} }
            if (a3 >= tau[i]) { int s_ = atomicAdd(&cnt[lq],1); if (s_<128){sidx[lq][s_]=m+3; skey[lq][s_]=a3;} }
        }
    }

    // exact rerank per query (wave-local); ties -> lower index (lax.top_k)
    #pragma unroll 1
    for (int i = 0; i < 8; ++i) {
        int lq = wid * 8 + i;
        int S = cnt[lq]; if (S > 128) S = 128;
        for (int p = lane; p < S; p += 64) {
            int m = sidx[lq][p];
            float km = skey[lq][p];
            int rank = 0;
            for (int j = 0; j < S; ++j) {
                float kj = skey[lq][j];
                int ij = sidx[lq][j];
                if (kj > km || (kj == km && ij < m)) rank++;
            }
            if (rank < KNN) outI[lq][rank] = m;
        }
    }
    __syncthreads();
    // write out 32 queries x 16 ranks
    #pragma unroll
    for (int h = 0; h < 2; ++h) {
        int lq = h * 16 + (t >> 4);
        idxo[(size_t)(qblk + lq) * KNN + (t & 15)] = outI[lq][t & 15];
    }
}

// ---------------- K2: gather + filter contraction as LDS-tiled GEMM ----------
// outp[q][d] = sum_{j=0..16} sum_c xT[nbr_j(q)][c] * Fbig[j][c][d]
// Tile: 64 queries x 64 d per block; K-loop over j (17) x c (64).
// Accumulation order (j outer, c ascending) identical to R6 => bit-stable.
#define CPAD 68
__global__ __launch_bounds__(256) void k_conv(const float* __restrict__ xT,
                                              const float* __restrict__ Fb,
                                              const int* __restrict__ idx,
                                              float* __restrict__ outp) {
    __shared__ float At[64][CPAD];
    __shared__ float Bt[64 * 64];
    int t = threadIdx.x;
    int q0 = blockIdx.x * 64;                 // tile base (same batch: 8192%64==0)
    int bbase = q0 & ~(NPTS - 1);             // batch row offset in xT
    int qi0 = (t >> 4) * 4;                   // query sub-block 0..60
    int dj0 = (t & 15) * 4;                   // d sub-block 0..60
    int r = t & 63;                           // gather row
    int s = t >> 6;                           // 16-float segment

    float acc[4][4];
    #pragma unroll
    for (int a = 0; a < 4; ++a)
        #pragma unroll
        for (int bb = 0; bb < 4; ++bb) acc[a][bb] = 0.f;

    for (int j = 0; j < 17; ++j) {
        // ---- stage A: gather 64 neighbor rows, store transposed ----
        {
            int qg = q0 + r;
            int nbr = (j < 16) ? (idx[(size_t)qg * KNN + j] & (NPTS - 1))
                               : (qg & (NPTS - 1));
            const float* src = xT + ((size_t)(bbase + nbr) * 64 + s * 16);
            float4 v0 = *(const float4*)(src);
            float4 v1 = *(const float4*)(src + 4);
            float4 v2 = *(const float4*)(src + 8);
            float4 v3 = *(const float4*)(src + 12);
            int c0 = s * 16;
            At[c0+ 0][r] = v0.x; At[c0+ 1][r] = v0.y; At[c0+ 2][r] = v0.z; At[c0+ 3][r] = v0.w;
            At[c0+ 4][r] = v1.x; At[c0+ 5][r] = v1.y; At[c0+ 6][r] = v1.z; At[c0+ 7][r] = v1.w;
            At[c0+ 8][r] = v2.x; At[c0+ 9][r] = v2.y; At[c0+10][r] = v2.z; At[c0+11][r] = v2.w;
            At[c0+12][r] = v3.x; At[c0+13][r] = v3.y; At[c0+14][r] = v3.z; At[c0+15][r] = v3.w;
        }
        // ---- stage B: copy F[j] (4096 floats) ----
        {
            const float* fj = Fb + j * 4096;
            #pragma unroll
            for (int u = 0; u < 4; ++u) {
                int e = u * 1024 + t * 4;
                *(float4*)&Bt[e] = *(const float4*)(fj + e);
            }
        }
        __syncthreads();
        // ---- compute: 64 k-steps ----
        #pragma unroll 8
        for (int k = 0; k < 64; ++k) {
            float4 av = *(const float4*)&At[k][qi0];
            float4 bv = *(const float4*)&Bt[k * 64 + dj0];
            acc[0][0] = fmaf(av.x, bv.x, acc[0][0]);
            acc[0][1] = fmaf(av.x, bv.y, acc[0][1]);
            acc[0][2] = fmaf(av.x, bv.z, acc[0][2]);
            acc[0][3] = fmaf(av.x, bv.w, acc[0][3]);
            acc[1][0] = fmaf(av.y, bv.x, acc[1][0]);
            acc[1][1] = fmaf(av.y, bv.y, acc[1][1]);
            acc[1][2] = fmaf(av.y, bv.z, acc[1][2]);
            acc[1][3] = fmaf(av.y, bv.w, acc[1][3]);
            acc[2][0] = fmaf(av.z, bv.x, acc[2][0]);
            acc[2][1] = fmaf(av.z, bv.y, acc[2][1]);
            acc[2][2] = fmaf(av.z, bv.z, acc[2][2]);
            acc[2][3] = fmaf(av.z, bv.w, acc[2][3]);
            acc[3][0] = fmaf(av.w, bv.x, acc[3][0]);
            acc[3][1] = fmaf(av.w, bv.y, acc[3][1]);
            acc[3][2] = fmaf(av.w, bv.z, acc[3][2]);
            acc[3][3] = fmaf(av.w, bv.w, acc[3][3]);
        }
        __syncthreads();
    }
    // ---- epilogue ----
    #pragma unroll
    for (int qi = 0; qi < 4; ++qi) {
        float4 o = make_float4(acc[qi][0], acc[qi][1], acc[qi][2], acc[qi][3]);
        *(float4*)(outp + (size_t)(q0 + qi0 + qi) * 64 + dj0) = o;
    }
}

// ---------------- K3: per-channel sum / sumsq ----------------
__global__ __launch_bounds__(256) void k_stats(const float* __restrict__ outp,
                                               float* __restrict__ sums) {
    __shared__ float ls[4][64], lss[4][64];
    int lane = threadIdx.x & 63, wid = threadIdx.x >> 6;
    int gw = blockIdx.x * 4 + wid;         // 1024 waves, 32 rows each
    float s = 0.f, ss = 0.f;
    for (int r = gw * 32; r < gw * 32 + 32; ++r) {
        float v = outp[(size_t)r * 64 + lane];
        s += v; ss = fmaf(v, v, ss);
    }
    ls[wid][lane] = s; lss[wid][lane] = ss;
    __syncthreads();
    if (wid == 0) {
        float a = 0.f, b2 = 0.f;
        for (int w = 0; w < 4; ++w) { a += ls[w][lane]; b2 += lss[w][lane]; }
        atomicAdd(&sums[lane], a);
        atomicAdd(&sums[64 + lane], b2);
    }
}

// ---------------- K4: BN + transpose (B,N,D) -> (B,D,N) ----------------
__global__ __launch_bounds__(256) void k_bn(const float* __restrict__ outp,
                                            const float* __restrict__ sums,
                                            const float* __restrict__ gamma,
                                            const float* __restrict__ beta,
                                            float* __restrict__ out) {
    __shared__ float tile[64][65];
    __shared__ float sa[64], sb[64];
    int lane = threadIdx.x & 63, wid = threadIdx.x >> 6;
    int b = blockIdx.x >> 7, nt = blockIdx.x & 127;
    int n0 = nt * 64;
    if (threadIdx.x < 64) {
        const float inv = 1.f / 32768.f;
        float mean = sums[threadIdx.x] * inv;
        float var = sums[64 + threadIdx.x] * inv - mean * mean;
        float rs = rsqrtf(var + 1e-5f);
        float a = rs * gamma[threadIdx.x];
        sa[threadIdx.x] = a;
        sb[threadIdx.x] = beta[threadIdx.x] - mean * a;
    }
    for (int rr = 0; rr < 16; ++rr) {
        int r = wid * 16 + rr;
        tile[r][lane] = outp[((size_t)(b * NPTS + n0 + r)) * 64 + lane];
    }
    __syncthreads();
    for (int rr = 0; rr < 16; ++rr) {
        int dr = wid * 16 + rr;
        out[((size_t)b * 64 + dr) * NPTS + n0 + lane] =
            fmaf(tile[lane][dr], sa[dr], sb[dr]);
    }
}

extern "C" void kernel_launch(void* const* d_in, const int* in_sizes, int n_in,
                              void* d_out, int out_size, void* d_ws, size_t ws_size,
                              hipStream_t stream) {
    (void)in_sizes; (void)n_in; (void)out_size; (void)ws_size;
    const float* x     = (const float*)d_in[0];  // (4,64,8192)
    const float* pos   = (const float*)d_in[1];  // (4,3,8192)
    const float* F     = (const float*)d_in[2];  // (16,64,64)
    const float* gamma = (const float*)d_in[3];  // (64,)
    const float* beta  = (const float*)d_in[4];  // (64,)
    float* out = (float*)d_out;                  // (4,64,8192)

    char* ws = (char*)d_ws;
    float* xT   = (float*)(ws + OFF_XT);
    float* Fb   = (float*)(ws + OFF_FBIG);
    float* sums = (float*)(ws + OFF_SUMS);
    int*   idx  = (int*)(ws + OFF_IDX);
    float* pre  = (float*)(ws + OFF_PRE);
    float* sqa  = (float*)(ws + OFF_SQ);   // aliases pre; consumed before conv

    k_prep_x<<<512, 256, 0, stream>>>(x, xT);
    k_prep_f<<<18, 256, 0, stream>>>(F, Fb, sums);
    k_prep_sq<<<128, 256, 0, stream>>>(pos, sqa);
    k_knn<<<1024, 256, 0, stream>>>(pos, sqa, idx);
    k_conv<<<512, 256, 0, stream>>>(xT, Fb, idx, pre);
    k_stats<<<256, 256, 0, stream>>>(pre, sums);
    k_bn<<<512, 256, 0, stream>>>(pre, sums, gamma, beta, out);
}

// Round 9
// 300.279 us; speedup vs baseline: 2.4976x; 1.0410x over previous
//
#include <hip/hip_runtime.h>
#include <hip/hip_bf16.h>

// Problem constants (B=4, C=64, N=8192, K=16, D=64)
#define NPTS 8192
#define NQ   32768      // B*N
#define KNN  16

// ws layout (bytes)
#define OFF_XT   0                      // B*N*C f32 = 8 MB  (x transposed to (B,N,C))
#define OFF_FBIG (8*1024*1024)          // 17*64*64 f32 = 278528 B (F with appended -sum(F))
#define OFF_SUMS (OFF_FBIG + 278528)    // 128 f32 (sum, sumsq per channel)
#define OFF_IDX  (OFF_SUMS + 512)       // B*N*16 int32 = 2 MB
#define OFF_PRE  (OFF_IDX + 2*1024*1024)// B*N*64 f32 = 8 MB (pre-BN output, (B*N, D))
// sq array (B*N f32 = 128 KB) ALIASES the start of PRE: k_prep_sq writes it,
// k_knn consumes it, then k_conv overwrites PRE — stream-ordered, safe.
#define OFF_SQ   OFF_PRE

// Reference fp32 key — numpy execution model (verified R6, absmax 0.0156):
//   sq[m]   = (x*x + y*y) + z*z                  -- non-fused (np.sum(pos*pos))
//   inner   = fma(z,z', fma(y,y', rnd(x*x')))    -- einsum AVX2 axpy FMA chain
//   negd    = ((2*inner) - sq_n) - sq_m          -- elementwise, left-to-right
__device__ __forceinline__ float sq3(float x, float y, float z) {
    #pragma clang fp contract(off)
    float xx = x * x;
    float yy = y * y;
    float zz = z * z;
    return (xx + yy) + zz;
}
__device__ __forceinline__ float negd2(float qx, float qy, float qz, float sqn,
                                       float mx, float my, float mz, float sqm) {
    #pragma clang fp contract(off)
    float p0 = qx * mx;
    float inn = __builtin_fmaf(qz, mz, __builtin_fmaf(qy, my, p0));
    float t = 2.0f * inn;
    float u = t - sqn;
    return u - sqm;
}
// Filter margin: cheap fused key c~ = 2<q,m> - sqm differs from (exact key +
// sqn) by <= ~1e-4 (few ulps of intermediates <= 216). 2*eps = 2e-3 is 20x
// conservative; superset proof needs two eps-steps (tau-side + member-side).
#define KEY_EPS2 2.0e-3f

// ---------------- K0a: transpose x (B,C,N) -> xT (B,N,C) ----------------
__global__ __launch_bounds__(256) void k_prep_x(const float* __restrict__ x,
                                                float* __restrict__ xT) {
    __shared__ float tile[64][65];
    int lane = threadIdx.x & 63, wid = threadIdx.x >> 6;
    int b = blockIdx.x >> 7, nt = blockIdx.x & 127;
    int n0 = nt * 64;
    for (int rr = 0; rr < 16; ++rr) {
        int c = wid * 16 + rr;
        tile[c][lane] = x[((size_t)b * 64 + c) * NPTS + n0 + lane];
    }
    __syncthreads();
    for (int rr = 0; rr < 16; ++rr) {
        int r = wid * 16 + rr;
        xT[((size_t)(b * NPTS + n0 + r)) * 64 + lane] = tile[lane][r];
    }
}

// ---------------- K0b: Fbig[j]=F[j] (j<16), Fbig[16]=-sum_k F[k]; zero sums ----
__global__ __launch_bounds__(256) void k_prep_f(const float* __restrict__ F,
                                                float* __restrict__ Fb,
                                                float* __restrict__ sums) {
    int j = blockIdx.x;
    if (j < 16) {
        for (int e = threadIdx.x; e < 4096; e += 256)
            Fb[j * 4096 + e] = F[j * 4096 + e];
    } else if (j == 16) {
        for (int e = threadIdx.x; e < 4096; e += 256) {
            float s = 0.f;
            for (int k = 0; k < 16; ++k) s += F[k * 4096 + e];
            Fb[16 * 4096 + e] = -s;
        }
    } else {
        if (threadIdx.x < 128) sums[threadIdx.x] = 0.f;
    }
}

// ---------------- K0c: per-point sq (exact reference rounding) ----------------
__global__ __launch_bounds__(256) void k_prep_sq(const float* __restrict__ pos,
                                                 float* __restrict__ sqa) {
    int g = blockIdx.x * 256 + threadIdx.x;   // 0..NQ-1
    int b = g >> 13, n = g & (NPTS - 1);
    const float* pb = pos + (size_t)b * 3 * NPTS;
    sqa[g] = sq3(pb[n], pb[NPTS + n], pb[2 * NPTS + n]);
}

// ---------------- K1: kNN, 8 queries/wave, cheap-key passes ------------------
// Pass1/2 use the fused 3-FMA key c~ (sqn shift dropped: ranking-invariant);
// exact reference keys computed once per survivor (phase A), then exact
// rerank (phase B). Margin KEY_EPS2 guarantees the survivor set supersets
// the true top-16 under the reference key.
__global__ __launch_bounds__(256) void k_knn(const float* __restrict__ pos,
                                             const float* __restrict__ sqa,
                                             int* __restrict__ idxo) {
    __shared__ int   cnt[32];
    __shared__ int   sidx[32][128];
    __shared__ float skey[32][128];
    __shared__ int   outI[32][16];
    int t = threadIdx.x, lane = t & 63, wid = t >> 6;
    int qblk = blockIdx.x * 32;               // 32 queries per block, same batch
    int b = qblk >> 13;
    const float* px = pos + (size_t)b * 3 * NPTS;
    const float* py = px + NPTS;
    const float* pz = py + NPTS;
    const float* sb = sqa + (size_t)b * NPTS;
    int n0 = (qblk & (NPTS - 1)) + wid * 8;   // this wave's first query

    float qxs[8], qys[8], qzs[8], sqs[8], tqx[8], tqy[8], tqz[8];
    #pragma unroll
    for (int i = 0; i < 8; ++i) {
        qxs[i] = px[n0 + i]; qys[i] = py[n0 + i];
        qzs[i] = pz[n0 + i]; sqs[i] = sb[n0 + i];
        tqx[i] = 2.0f * qxs[i]; tqy[i] = 2.0f * qys[i]; tqz[i] = 2.0f * qzs[i];
    }
    if (lane < 8) cnt[wid * 8 + lane] = 0;    // wave-private: no block sync
    if (lane < 16) {
        #pragma unroll
        for (int i = 0; i < 8; ++i) outI[wid * 8 + i][lane] = n0 + i;  // fallback
    }

    // pass 1: per-lane max of cheap key, per query (3 fma + fmax per cand)
    float lm[8];
    #pragma unroll
    for (int i = 0; i < 8; ++i) lm[i] = -3.4e38f;
    for (int it = 0; it < 32; ++it) {
        int m = it * 256 + lane * 4;
        float4 X = *(const float4*)(px + m);
        float4 Y = *(const float4*)(py + m);
        float4 Z = *(const float4*)(pz + m);
        float4 S = *(const float4*)(sb + m);
        #pragma unroll
        for (int i = 0; i < 8; ++i) {
            float a0 = __builtin_fmaf(tqx[i], X.x, __builtin_fmaf(tqy[i], Y.x, __builtin_fmaf(tqz[i], Z.x, -S.x)));
            float a1 = __builtin_fmaf(tqx[i], X.y, __builtin_fmaf(tqy[i], Y.y, __builtin_fmaf(tqz[i], Z.y, -S.y)));
            float a2 = __builtin_fmaf(tqx[i], X.z, __builtin_fmaf(tqy[i], Y.z, __builtin_fmaf(tqz[i], Z.z, -S.z)));
            float a3 = __builtin_fmaf(tqx[i], X.w, __builtin_fmaf(tqy[i], Y.w, __builtin_fmaf(tqz[i], Z.w, -S.w)));
            lm[i] = fmaxf(lm[i], fmaxf(fmaxf(a0, a1), fmaxf(a2, a3)));
        }
    }

    // thr[i] = (16th largest of 64 lane maxima) - 2*eps
    float thr[8];
    #pragma unroll
    for (int i = 0; i < 8; ++i) {
        float val = lm[i], tv = 0.f;
        for (int r = 0; r < 16; ++r) {
            float mm = val;
            mm = fmaxf(mm, __shfl_xor(mm, 1, 64));
            mm = fmaxf(mm, __shfl_xor(mm, 2, 64));
            mm = fmaxf(mm, __shfl_xor(mm, 4, 64));
            mm = fmaxf(mm, __shfl_xor(mm, 8, 64));
            mm = fmaxf(mm, __shfl_xor(mm, 16, 64));
            mm = fmaxf(mm, __shfl_xor(mm, 32, 64));
            tv = mm;
            if (val == mm) val = -3.4e38f;   // ties pop together: tau shrinks -> superset
        }
        thr[i] = tv - KEY_EPS2;
    }

    // pass 2: collect survivor indices (cheap key only; expected ~20-45/query)
    for (int it = 0; it < 32; ++it) {
        int m = it * 256 + lane * 4;
        float4 X = *(const float4*)(px + m);
        float4 Y = *(const float4*)(py + m);
        float4 Z = *(const float4*)(pz + m);
        float4 S = *(const float4*)(sb + m);
        #pragma unroll
        for (int i = 0; i < 8; ++i) {
            int lq = wid * 8 + i;
            float a0 = __builtin_fmaf(tqx[i], X.x, __builtin_fmaf(tqy[i], Y.x, __builtin_fmaf(tqz[i], Z.x, -S.x)));
            float a1 = __builtin_fmaf(tqx[i], X.y, __builtin_fmaf(tqy[i], Y.y, __builtin_fmaf(tqz[i], Z.y, -S.y)));
            float a2 = __builtin_fmaf(tqx[i], X.z, __builtin_fmaf(tqy[i], Y.z, __builtin_fmaf(tqz[i], Z.z, -S.z)));
            float a3 = __builtin_fmaf(tqx[i], X.w, __builtin_fmaf(tqy[i], Y.w, __builtin_fmaf(tqz[i], Z.w, -S.w)));
            if (a0 >= thr[i]) { int s_ = atomicAdd(&cnt[lq],1); if (s_<128) sidx[lq][s_] = m; }
            if (a1 >= thr[i]) { int s_ = atomicAdd(&cnt[lq],1); if (s_<128) sidx[lq][s_] = m+1; }
            if (a2 >= thr[i]) { int s_ = atomicAdd(&cnt[lq],1); if (s_<128) sidx[lq][s_] = m+2; }
            if (a3 >= thr[i]) { int s_ = atomicAdd(&cnt[lq],1); if (s_<128) sidx[lq][s_] = m+3; }
        }
    }
    __syncthreads();

    // phase A: exact reference key per survivor (scattered L2 loads, rare)
    #pragma unroll 1
    for (int i = 0; i < 8; ++i) {
        int lq = wid * 8 + i;
        int S = cnt[lq]; if (S > 128) S = 128;
        for (int p = lane; p < S; p += 64) {
            int m = sidx[lq][p];
            skey[lq][p] = negd2(qxs[i], qys[i], qzs[i], sqs[i],
                                px[m], py[m], pz[m], sb[m]);
        }
    }
    __syncthreads();

    // phase B: exact rerank; ties -> lower index (lax.top_k semantics)
    #pragma unroll 1
    for (int i = 0; i < 8; ++i) {
        int lq = wid * 8 + i;
        int S = cnt[lq]; if (S > 128) S = 128;
        for (int p = lane; p < S; p += 64) {
            int m = sidx[lq][p];
            float km = skey[lq][p];
            int rank = 0;
            for (int j = 0; j < S; ++j) {
                float kj = skey[lq][j];
                int ij = sidx[lq][j];
                if (kj > km || (kj == km && ij < m)) rank++;
            }
            if (rank < KNN) outI[lq][rank] = m;
        }
    }
    __syncthreads();
    // write out 32 queries x 16 ranks
    #pragma unroll
    for (int h = 0; h < 2; ++h) {
        int lq = h * 16 + (t >> 4);
        idxo[(size_t)(qblk + lq) * KNN + (t & 15)] = outI[lq][t & 15];
    }
}

// ---------------- K2: gather + filter contraction as LDS-tiled GEMM ----------
// outp[q][d] = sum_{j=0..16} sum_c xT[nbr_j(q)][c] * Fbig[j][c][d]
// Tile: 64 queries x 64 d per block; K-loop over j (17) x c (64).
// Accumulation order (j outer, c ascending) identical to R6 => bit-stable.
#define CPAD 68
__global__ __launch_bounds__(256) void k_conv(const float* __restrict__ xT,
                                              const float* __restrict__ Fb,
                                              const int* __restrict__ idx,
                                              float* __restrict__ outp) {
    __shared__ float At[64][CPAD];
    __shared__ float Bt[64 * 64];
    int t = threadIdx.x;
    int q0 = blockIdx.x * 64;                 // tile base (same batch: 8192%64==0)
    int bbase = q0 & ~(NPTS - 1);             // batch row offset in xT
    int qi0 = (t >> 4) * 4;                   // query sub-block 0..60
    int dj0 = (t & 15) * 4;                   // d sub-block 0..60
    int r = t & 63;                           // gather row
    int s = t >> 6;                           // 16-float segment

    float acc[4][4];
    #pragma unroll
    for (int a = 0; a < 4; ++a)
        #pragma unroll
        for (int bb = 0; bb < 4; ++bb) acc[a][bb] = 0.f;

    for (int j = 0; j < 17; ++j) {
        // ---- stage A: gather 64 neighbor rows, store transposed ----
        {
            int qg = q0 + r;
            int nbr = (j < 16) ? (idx[(size_t)qg * KNN + j] & (NPTS - 1))
                               : (qg & (NPTS - 1));
            const float* src = xT + ((size_t)(bbase + nbr) * 64 + s * 16);
            float4 v0 = *(const float4*)(src);
            float4 v1 = *(const float4*)(src + 4);
            float4 v2 = *(const float4*)(src + 8);
            float4 v3 = *(const float4*)(src + 12);
            int c0 = s * 16;
            At[c0+ 0][r] = v0.x; At[c0+ 1][r] = v0.y; At[c0+ 2][r] = v0.z; At[c0+ 3][r] = v0.w;
            At[c0+ 4][r] = v1.x; At[c0+ 5][r] = v1.y; At[c0+ 6][r] = v1.z; At[c0+ 7][r] = v1.w;
            At[c0+ 8][r] = v2.x; At[c0+ 9][r] = v2.y; At[c0+10][r] = v2.z; At[c0+11][r] = v2.w;
            At[c0+12][r] = v3.x; At[c0+13][r] = v3.y; At[c0+14][r] = v3.z; At[c0+15][r] = v3.w;
        }
        // ---- stage B: copy F[j] (4096 floats) ----
        {
            const float* fj = Fb + j * 4096;
            #pragma unroll
            for (int u = 0; u < 4; ++u) {
                int e = u * 1024 + t * 4;
                *(float4*)&Bt[e] = *(const float4*)(fj + e);
            }
        }
        __syncthreads();
        // ---- compute: 64 k-steps ----
        #pragma unroll 8
        for (int k = 0; k < 64; ++k) {
            float4 av = *(const float4*)&At[k][qi0];
            float4 bv = *(const float4*)&Bt[k * 64 + dj0];
            acc[0][0] = fmaf(av.x, bv.x, acc[0][0]);
            acc[0][1] = fmaf(av.x, bv.y, acc[0][1]);
            acc[0][2] = fmaf(av.x, bv.z, acc[0][2]);
            acc[0][3] = fmaf(av.x, bv.w, acc[0][3]);
            acc[1][0] = fmaf(av.y, bv.x, acc[1][0]);
            acc[1][1] = fmaf(av.y, bv.y, acc[1][1]);
            acc[1][2] = fmaf(av.y, bv.z, acc[1][2]);
            acc[1][3] = fmaf(av.y, bv.w, acc[1][3]);
            acc[2][0] = fmaf(av.z, bv.x, acc[2][0]);
            acc[2][1] = fmaf(av.z, bv.y, acc[2][1]);
            acc[2][2] = fmaf(av.z, bv.z, acc[2][2]);
            acc[2][3] = fmaf(av.z, bv.w, acc[2][3]);
            acc[3][0] = fmaf(av.w, bv.x, acc[3][0]);
            acc[3][1] = fmaf(av.w, bv.y, acc[3][1]);
            acc[3][2] = fmaf(av.w, bv.z, acc[3][2]);
            acc[3][3] = fmaf(av.w, bv.w, acc[3][3]);
        }
        __syncthreads();
    }
    // ---- epilogue ----
    #pragma unroll
    for (int qi = 0; qi < 4; ++qi) {
        float4 o = make_float4(acc[qi][0], acc[qi][1], acc[qi][2], acc[qi][3]);
        *(float4*)(outp + (size_t)(q0 + qi0 + qi) * 64 + dj0) = o;
    }
}

// ---------------- K3: per-channel sum / sumsq ----------------
__global__ __launch_bounds__(256) void k_stats(const float* __restrict__ outp,
                                               float* __restrict__ sums) {
    __shared__ float ls[4][64], lss[4][64];
    int lane = threadIdx.x & 63, wid = threadIdx.x >> 6;
    int gw = blockIdx.x * 4 + wid;         // 1024 waves, 32 rows each
    float s = 0.f, ss = 0.f;
    for (int r = gw * 32; r < gw * 32 + 32; ++r) {
        float v = outp[(size_t)r * 64 + lane];
        s += v; ss = fmaf(v, v, ss);
    }
    ls[wid][lane] = s; lss[wid][lane] = ss;
    __syncthreads();
    if (wid == 0) {
        float a = 0.f, b2 = 0.f;
        for (int w = 0; w < 4; ++w) { a += ls[w][lane]; b2 += lss[w][lane]; }
        atomicAdd(&sums[lane], a);
        atomicAdd(&sums[64 + lane], b2);
    }
}

// ---------------- K4: BN + transpose (B,N,D) -> (B,D,N) ----------------
__global__ __launch_bounds__(256) void k_bn(const float* __restrict__ outp,
                                            const float* __restrict__ sums,
                                            const float* __restrict__ gamma,
                                            const float* __restrict__ beta,
                                            float* __restrict__ out) {
    __shared__ float tile[64][65];
    __shared__ float sa[64], sb[64];
    int lane = threadIdx.x & 63, wid = threadIdx.x >> 6;
    int b = blockIdx.x >> 7, nt = blockIdx.x & 127;
    int n0 = nt * 64;
    if (threadIdx.x < 64) {
        const float inv = 1.f / 32768.f;
        float mean = sums[threadIdx.x] * inv;
        float var = sums[64 + threadIdx.x] * inv - mean * mean;
        float rs = rsqrtf(var + 1e-5f);
        float a = rs * gamma[threadIdx.x];
        sa[threadIdx.x] = a;
        sb[threadIdx.x] = beta[threadIdx.x] - mean * a;
    }
    for (int rr = 0; rr < 16; ++rr) {
        int r = wid * 16 + rr;
        tile[r][lane] = outp[((size_t)(b * NPTS + n0 + r)) * 64 + lane];
    }
    __syncthreads();
    for (int rr = 0; rr < 16; ++rr) {
        int dr = wid * 16 + rr;
        out[((size_t)b * 64 + dr) * NPTS + n0 + lane] =
            fmaf(tile[lane][dr], sa[dr], sb[dr]);
    }
}

extern "C" void kernel_launch(void* const* d_in, const int* in_sizes, int n_in,
                              void* d_out, int out_size, void* d_ws, size_t ws_size,
                              hipStream_t stream) {
    (void)in_sizes; (void)n_in; (void)out_size; (void)ws_size;
    const float* x     = (const float*)d_in[0];  // (4,64,8192)
    const float* pos   = (const float*)d_in[1];  // (4,3,8192)
    const float* F     = (const float*)d_in[2];  // (16,64,64)
    const float* gamma = (const float*)d_in[3];  // (64,)
    const float* beta  = (const float*)d_in[4];  // (64,)
    float* out = (float*)d_out;                  // (4,64,8192)

    char* ws = (char*)d_ws;
    float* xT   = (float*)(ws + OFF_XT);
    float* Fb   = (float*)(ws + OFF_FBIG);
    float* sums = (float*)(ws + OFF_SUMS);
    int*   idx  = (int*)(ws + OFF_IDX);
    float* pre  = (float*)(ws + OFF_PRE);
    float* sqa  = (float*)(ws + OFF_SQ);   // aliases pre; consumed before conv

    k_prep_x<<<512, 256, 0, stream>>>(x, xT);
    k_prep_f<<<18, 256, 0, stream>>>(F, Fb, sums);
    k_prep_sq<<<128, 256, 0, stream>>>(pos, sqa);
    k_knn<<<1024, 256, 0, stream>>>(pos, sqa, idx);
    k_conv<<<512, 256, 0, stream>>>(xT, Fb, idx, pre);
    k_stats<<<256, 256, 0, stream>>>(pre, sums);
    k_bn<<<512, 256, 0, stream>>>(pre, sums, gamma, beta, out);
}